// Round 11
// baseline (201.597 us; speedup 1.0000x reference)
//
#include <hip/hip_runtime.h>

#define NB 512
#define NN 50
#define ND 64
#define LOG2E 1.44269504088896340736f

typedef short bf16x8 __attribute__((ext_vector_type(8)));
typedef float f32x4  __attribute__((ext_vector_type(4)));
typedef _Float16 h2  __attribute__((ext_vector_type(2)));

// ---- manual LDS arena (bytes) ----
// xa  u16 [50][72]  7200 @ 0     : layer input x / att1 (bf16 A-rows; frag reads
//                                  overhang rows 50-63 into xb region = finite garbage,
//                                  contained to discarded C-rows >= 50)
// xb  u16 [50][72]  7200 @ 7200  : attRaw (ph2 out -> ph3 A); DEDICATED region =>
//                                  no barrier between ph2 reads and xb writes
// wa1t u16[64][72]  9216 @ 14400 : Wa1^T [n][k]
// wa2t u16[64][72]  9216 @ 23616 : Wa2^T [n][k]
// wot  u16[64][72]  9216 @ 32832 : W1^T then W2^T
// kx  f16 [64][100] 12800 @ 42048: per d: 25 records [4p..4p+3]=Ek2p,Ek2p+1,ek2p,ek2p+1
//                                  (200 B rows: 8B-aligned b64, 16 even bank-bases, CF)
// xt  f16 [64][52]  6656 @ 54848 : x^T [d][j] (104 B rows: h2-pair b64 merge, CF banks)
// alias yF f32[50][64] 12800 @ 42048 (over kx; kx dead after ph2-L1, barrier-guarded)
#define OFF_XA    0
#define OFF_XB    7200
#define OFF_WA1T  14400
#define OFF_WA2T  23616
#define OFF_WOT   32832
#define OFF_KX    42048
#define OFF_XT    54848
#define OFF_YF    42048
#define SMEM_BYTES 61504
#define KXS 100
#define XTS 52

__device__ __forceinline__ float bfu(unsigned short u) {
    union { unsigned int i; float f; } v; v.i = ((unsigned int)u) << 16; return v.f;
}
__device__ __forceinline__ unsigned int f2bfbits(float f) {
    union { float f; unsigned int i; } v; v.f = f;
    unsigned int x = v.i;
    return (x + 0x7FFFu + ((x >> 16) & 1u)) >> 16;
}

// One block per batch, 1024 threads = 16 waves (2 blocks/CU = 32 waves/CU).
// MFMA 16x16x32_bf16, M padded 50->64, 4x4 tile grid, 1 tile/wave.
// Phase 2 keeps phase 1's C-fragment ownership (rows i0..i0+3 at col dcol);
// rho = exp2(-0.99 q') stays in VGPRs. w_ij = Eq*max(Ek, rho*ek); Eq cancels.
// 7 barriers total (was 9): ph0 | ph1(+kx wr) | ph2(+xb wr) | ph3 | per layer.
// NO unions over vector types (r8: scratch round-trips -> 300 MB HBM, 2.5x).
__global__ __launch_bounds__(1024, 8)
void att2_kernel(const float* __restrict__ emb,
                 const float* __restrict__ wa1, const float* __restrict__ ba1,
                 const float* __restrict__ wa2, const float* __restrict__ ba2,
                 const float* __restrict__ w1,  const float* __restrict__ b1,
                 const float* __restrict__ w2,  const float* __restrict__ b2,
                 float* __restrict__ out)
{
    __shared__ __align__(16) unsigned char smem[SMEM_BYTES];
    unsigned short* xa   = (unsigned short*)(smem + OFF_XA);
    unsigned short* xb   = (unsigned short*)(smem + OFF_XB);
    unsigned short* wa1t = (unsigned short*)(smem + OFF_WA1T);
    unsigned short* wa2t = (unsigned short*)(smem + OFF_WA2T);
    unsigned short* wot  = (unsigned short*)(smem + OFF_WOT);
    _Float16*       kx   = (_Float16*)(smem + OFF_KX);
    _Float16*       xt   = (_Float16*)(smem + OFF_XT);
    float*          yF   = (float*)(smem + OFF_YF);            // alias over kx

    const int b    = blockIdx.x;
    const int tid  = threadIdx.x;
    const int w    = tid >> 6;        // wave 0..15
    const int lane = tid & 63;
    const int ln   = lane & 15;       // MFMA row/col in tile
    const int qd   = lane >> 4;       // MFMA quad
    const int tm   = w >> 2;          // M-tile
    const int tn   = w & 3;           // N-tile
    const int dcol = tn * 16 + ln;    // owned column
    const int i0   = tm * 16 + qd * 4;// first owned row

    const float* embB = emb + (size_t)b * (NN + 1) * ND;

    // ---- ph0: stage x (bf16 rows + f16 transposed), W^T (no pad zeroing) ----
    for (int u = tid; u < (NN * ND) / 2; u += 1024) {
        float2 v = *(const float2*)(embB + ND + 2 * u);
        int i = (2 * u) >> 6, c = (2 * u) & 63;
        *(unsigned int*)&xa[i * 72 + c] = (f2bfbits(v.y) << 16) | f2bfbits(v.x);
        xt[c * XTS + i]       = (_Float16)v.x;
        xt[(c + 1) * XTS + i] = (_Float16)v.y;
    }
    for (int u = tid; u < ND * ND; u += 1024) {
        int k = u >> 6, n = u & 63;
        wa1t[n * 72 + k] = (unsigned short)f2bfbits(wa1[u]);
        wa2t[n * 72 + k] = (unsigned short)f2bfbits(wa2[u]);
        wot [n * 72 + k] = (unsigned short)f2bfbits(w1[u]);
    }
    __syncthreads();                                           // b0

    const float bq = ba1[dcol];
    const float bk = ba2[dcol];

    for (int L = 0; L < 2; ++L) {
        // ---- ph1: q/k GEMM on MFMA + exp epilogue (kx writes same epoch) ----
        // (L==1: also restage wot=W2; prev wot readers ended >=1 barrier ago,
        //  next readers are 2 barriers ahead)
        if (L == 1) {
            for (int u = tid; u < ND * ND; u += 1024) {
                int k = u >> 6, n = u & 63;
                wot[n * 72 + k] = (unsigned short)f2bfbits(w2[u]);
            }
        }
        float rho[4];
        {
            const bf16x8 a0 = *(const bf16x8*)&xa[(tm * 16 + ln) * 72 + qd * 8];
            const bf16x8 a1 = *(const bf16x8*)&xa[(tm * 16 + ln) * 72 + 32 + qd * 8];
            f32x4 accq = {bq, bq, bq, bq};
            f32x4 acck = {bk, bk, bk, bk};

            bf16x8 bf_;
            bf_ = *(const bf16x8*)&wa1t[dcol * 72 + qd * 8];
            accq = __builtin_amdgcn_mfma_f32_16x16x32_bf16(a0, bf_, accq, 0, 0, 0);
            bf_ = *(const bf16x8*)&wa1t[dcol * 72 + 32 + qd * 8];
            accq = __builtin_amdgcn_mfma_f32_16x16x32_bf16(a1, bf_, accq, 0, 0, 0);
            bf_ = *(const bf16x8*)&wa2t[dcol * 72 + qd * 8];
            acck = __builtin_amdgcn_mfma_f32_16x16x32_bf16(a0, bf_, acck, 0, 0, 0);
            bf_ = *(const bf16x8*)&wa2t[dcol * 72 + 32 + qd * 8];
            acck = __builtin_amdgcn_mfma_f32_16x16x32_bf16(a1, bf_, acck, 0, 0, 0);

            _Float16 Ekf[4], ekf[4];
#pragma unroll
            for (int reg = 0; reg < 4; ++reg) {
                rho[reg] = __builtin_exp2f(accq[reg] * (-0.99f * LOG2E));
                float kp = acck[reg] * LOG2E;
                Ekf[reg] = (_Float16)__builtin_exp2f(kp);
                ekf[reg] = (_Float16)__builtin_exp2f(0.01f * kp);
            }
            // kx records: h2 index unit; rows i0..i0+3 -> records i0/2, i0/2+1.
            // Per-pair guards: at stride 100, pad-row writes would corrupt the
            // next d's row.
            h2* kxh = (h2*)(kx + dcol * KXS);
            if (i0 < NN) {                 // j = i0, i0+1  (i0=48 -> offsets 96..99 OK)
                kxh[i0]     = (h2){Ekf[0], Ekf[1]};
                kxh[i0 + 1] = (h2){ekf[0], ekf[1]};
            }
            if (i0 + 2 < NN) {             // j = i0+2, i0+3
                kxh[i0 + 2] = (h2){Ekf[2], Ekf[3]};
                kxh[i0 + 3] = (h2){ekf[2], ekf[3]};
            }
        }
        __syncthreads();                                       // b1 / b4

        // ---- ph2: packed-f16 softmax-weighted sum + xb write (same epoch) ----
        {
            h2 rho2[4], num2[4], den2[4];
#pragma unroll
            for (int r = 0; r < 4; ++r) {
                _Float16 rv = (_Float16)rho[r];
                rho2[r] = (h2){rv, rv};
                num2[r] = (h2)0.f;
                den2[r] = (h2)0.f;
            }
            const h2* kxP = (const h2*)(kx + dcol * KXS);
            const h2* xP  = (const h2*)(xt + dcol * XTS);
            for (int p = 0; p < NN / 2; ++p) {
                h2 Ek2 = kxP[2 * p];        // merged ds_read_b64 with next
                h2 ek2 = kxP[2 * p + 1];
                h2 x2  = xP[p];
#pragma unroll
                for (int r = 0; r < 4; ++r) {
                    h2 wv = __builtin_elementwise_max(rho2[r] * ek2, Ek2);
                    den2[r] = den2[r] + wv;
                    num2[r] = wv * x2 + num2[r];        // v_pk_fma_f16
                }
            }
#pragma unroll
            for (int reg = 0; reg < 4; ++reg) {
                const int i = i0 + reg;
                if (i < NN) {
                    float nu = (float)num2[reg].x + (float)num2[reg].y;
                    float de = (float)den2[reg].x + (float)den2[reg].y;
                    xb[i * 72 + dcol] = (unsigned short)f2bfbits(nu / de);
                }
            }
        }
        __syncthreads();                                       // b2 / b5

        // ---- ph3: y = att @ Wl + bl on MFMA ----
        // (xb frag reads overhang rows >= 50 into wa1t = finite garbage,
        //  contained to discarded C-rows)
        {
            const bf16x8 c0 = *(const bf16x8*)&xb[(tm * 16 + ln) * 72 + qd * 8];
            const bf16x8 c1 = *(const bf16x8*)&xb[(tm * 16 + ln) * 72 + 32 + qd * 8];
            const float bov = (L ? b2 : b1)[dcol];
            f32x4 y = {bov, bov, bov, bov};

            bf16x8 bf_;
            bf_ = *(const bf16x8*)&wot[dcol * 72 + qd * 8];
            y = __builtin_amdgcn_mfma_f32_16x16x32_bf16(c0, bf_, y, 0, 0, 0);
            bf_ = *(const bf16x8*)&wot[dcol * 72 + 32 + qd * 8];
            y = __builtin_amdgcn_mfma_f32_16x16x32_bf16(c1, bf_, y, 0, 0, 0);

            if (L == 0) {
                // att1 -> xa (bf16 A-rows, guarded) + xt (f16 [d][j], guarded)
#pragma unroll
                for (int reg = 0; reg < 4; ++reg) {
                    const int i = i0 + reg;
                    if (i < NN) {
                        xa[i * 72 + dcol] = (unsigned short)f2bfbits(y[reg]);
                        xt[dcol * XTS + i] = (_Float16)y[reg];
                    }
                }
                __syncthreads();                               // b3
            } else {
                // stage fp32 y over dead kx, then coalesced residual + store
#pragma unroll
                for (int reg = 0; reg < 4; ++reg) {
                    const int i = i0 + reg;
                    if (i < NN) yF[i * 64 + dcol] = y[reg];
                }
                __syncthreads();                               // b6
                for (int idx = tid; idx < NN * ND; idx += 1024) {
                    const int i  = idx >> 6;
                    const int dd = idx & 63;
                    float e0   = embB[dd];
                    float ie   = embB[ND + idx];
                    float att1 = bfu(xa[i * 72 + dd]);
                    float o    = fmaf(e0, ie, yF[idx] + att1);
                    o = fmaxf(o, 0.01f * o);
                    out[(size_t)b * (NN * ND) + idx] = o;
                }
            }
        }
    }
}

extern "C" void kernel_launch(void* const* d_in, const int* in_sizes, int n_in,
                              void* d_out, int out_size, void* d_ws, size_t ws_size,
                              hipStream_t stream) {
    const float* emb = (const float*)d_in[0];
    const float* wa1 = (const float*)d_in[1];
    const float* ba1 = (const float*)d_in[2];
    const float* wa2 = (const float*)d_in[3];
    const float* ba2 = (const float*)d_in[4];
    const float* w1  = (const float*)d_in[5];
    const float* b1  = (const float*)d_in[6];
    const float* w2  = (const float*)d_in[7];
    const float* b2  = (const float*)d_in[8];
    float* out = (float*)d_out;

    att2_kernel<<<NB, 1024, 0, stream>>>(emb, wa1, ba1, wa2, ba2, w1, b1, w2, b2, out);
}

// Round 12
// 95.841 us; speedup vs baseline: 2.1035x; 2.1035x over previous
//
#include <hip/hip_runtime.h>

#define NB 512
#define NN 50
#define ND 64
#define LOG2E 1.44269504088896340736f

typedef short bf16x8 __attribute__((ext_vector_type(8)));
typedef float f32x4  __attribute__((ext_vector_type(4)));
typedef _Float16 h2  __attribute__((ext_vector_type(2)));

// ---- manual LDS arena (bytes) ----  [r10 layout — VERIFIED GOOD, do not restructure:
// r11's 50-row/dedicated-xb restructure retriggered r8-style scratch spills
// (~550 MB HBM traffic, 4x regression) despite no unions. Counters, not source
// inspection, are the only reliable spill detector at the (1024,8) VGPR budget.]
// xa  u16 [64][72]  9216 @ 0     : layer input x / att1 (bf16 MFMA-A rows; pad rows zeroed once)
// wa1t u16[64][72]  9216 @ 9216  : Wa1^T [n][k]
// wa2t u16[64][72]  9216 @ 18432 : Wa2^T [n][k]
// wot  u16[64][72]  9216 @ 27648 : W1^T then W2^T
// kx  f16 [64][116] 14848 @ 36864: per d, records [4p..4p+3] = Ek_2p,Ek_2p+1,ek_2p,ek_2p+1
//                                  (stride 232 B: 8B-aligned b64 reads, 16 even bank-bases -> conflict-free)
// xt  f16 [64][56]  7168 @ 51712 : x transposed [d][j] (112 B rows, 16B-aligned, 2-way banks = free)
// alias xb u16[64][72] 9216 @ 36864 (over kx head; kx dead after ph2, barrier-guarded)
// alias yF f32[50][64] 12800 @ 46080 (over kx tail + xt; both dead in L1 ph3; disjoint from xb/wot)
#define OFF_XA    0
#define OFF_WA1T  9216
#define OFF_WA2T  18432
#define OFF_WOT   27648
#define OFF_KX    36864
#define OFF_XT    51712
#define OFF_XB    36864
#define OFF_YF    46080
#define SMEM_BYTES 58880

__device__ __forceinline__ float bfu(unsigned short u) {
    union { unsigned int i; float f; } v; v.i = ((unsigned int)u) << 16; return v.f;
}
__device__ __forceinline__ unsigned int f2bfbits(float f) {
    union { float f; unsigned int i; } v; v.f = f;
    unsigned int x = v.i;
    return (x + 0x7FFFu + ((x >> 16) & 1u)) >> 16;
}

// One block per batch, 1024 threads = 16 waves (2 blocks/CU = 32 waves/CU = max).
// MFMA 16x16x32_bf16, M padded 50->64, 4x4 tile grid, 1 tile/wave.
// Phase 2 inherits phase 1's C-fragment ownership: thread (wave w, lane) owns
// rows i0..i0+3 (i0 = tm*16+qd*4) at column dcol = tn*16+ln; rho = exp2(-0.99q')
// stays in VGPRs across the barrier (no qrho LDS round trip). Uniform 4 rows:
// pad rows >= 50 compute finite garbage contained to discarded C-rows.
// w_ij = Eq*max(Ek, rho*ek); Eq cancels in num/den.
// NO unions over vector types (r8: scratch round-trips -> 300 MB HBM, 2.5x).
__global__ __launch_bounds__(1024, 8)
void att2_kernel(const float* __restrict__ emb,
                 const float* __restrict__ wa1, const float* __restrict__ ba1,
                 const float* __restrict__ wa2, const float* __restrict__ ba2,
                 const float* __restrict__ w1,  const float* __restrict__ b1,
                 const float* __restrict__ w2,  const float* __restrict__ b2,
                 float* __restrict__ out)
{
    __shared__ __align__(16) unsigned char smem[SMEM_BYTES];
    unsigned short* xa   = (unsigned short*)(smem + OFF_XA);
    unsigned short* wa1t = (unsigned short*)(smem + OFF_WA1T);
    unsigned short* wa2t = (unsigned short*)(smem + OFF_WA2T);
    unsigned short* wot  = (unsigned short*)(smem + OFF_WOT);
    _Float16*       kx   = (_Float16*)(smem + OFF_KX);
    _Float16*       xt   = (_Float16*)(smem + OFF_XT);
    unsigned short* xb   = (unsigned short*)(smem + OFF_XB);   // alias
    float*          yF   = (float*)(smem + OFF_YF);            // alias

    const int b    = blockIdx.x;
    const int tid  = threadIdx.x;
    const int w    = tid >> 6;        // wave 0..15
    const int lane = tid & 63;
    const int ln   = lane & 15;       // MFMA row/col in tile
    const int qd   = lane >> 4;       // MFMA quad
    const int tm   = w >> 2;          // M-tile
    const int tn   = w & 3;           // N-tile
    const int dcol = tn * 16 + ln;    // owned column (phases 1,2,3)
    const int i0   = tm * 16 + qd * 4;// first owned row

    const float* embB = emb + (size_t)b * (NN + 1) * ND;

    // ---- phase 0: stage x (bf16 rows + f16 transposed), zero xa pad, W^T ----
    for (int u = tid; u < (NN * ND) / 2; u += 1024) {
        float2 v = *(const float2*)(embB + ND + 2 * u);
        int i = (2 * u) >> 6, c = (2 * u) & 63;
        *(unsigned int*)&xa[i * 72 + c] = (f2bfbits(v.y) << 16) | f2bfbits(v.x);
        xt[c * 56 + i]       = (_Float16)v.x;
        xt[(c + 1) * 56 + i] = (_Float16)v.y;
    }
    for (int u = tid; u < 14 * 72; u += 1024) xa[NN * 72 + u] = 0;   // A pad rows
    for (int u = tid; u < ND * ND; u += 1024) {
        int k = u >> 6, n = u & 63;
        wa1t[n * 72 + k] = (unsigned short)f2bfbits(wa1[u]);
        wa2t[n * 72 + k] = (unsigned short)f2bfbits(wa2[u]);
        wot [n * 72 + k] = (unsigned short)f2bfbits(w1[u]);
    }
    __syncthreads();

    const float bq = ba1[dcol];
    const float bk = ba2[dcol];

    for (int L = 0; L < 2; ++L) {
        if (L == 1) {   // restage W2^T; last wot read was before the prev barrier
            for (int u = tid; u < ND * ND; u += 1024) {
                int k = u >> 6, n = u & 63;
                wot[n * 72 + k] = (unsigned short)f2bfbits(w2[u]);
            }
        }

        // ---- phase 1: q/k GEMM on MFMA + exp epilogue (rho stays in regs) ----
        float rho[4];
        {
            const bf16x8 a0 = *(const bf16x8*)&xa[(tm * 16 + ln) * 72 + qd * 8];
            const bf16x8 a1 = *(const bf16x8*)&xa[(tm * 16 + ln) * 72 + 32 + qd * 8];
            f32x4 accq = {bq, bq, bq, bq};
            f32x4 acck = {bk, bk, bk, bk};

            bf16x8 bf_;
            bf_ = *(const bf16x8*)&wa1t[dcol * 72 + qd * 8];
            accq = __builtin_amdgcn_mfma_f32_16x16x32_bf16(a0, bf_, accq, 0, 0, 0);
            bf_ = *(const bf16x8*)&wa1t[dcol * 72 + 32 + qd * 8];
            accq = __builtin_amdgcn_mfma_f32_16x16x32_bf16(a1, bf_, accq, 0, 0, 0);
            bf_ = *(const bf16x8*)&wa2t[dcol * 72 + qd * 8];
            acck = __builtin_amdgcn_mfma_f32_16x16x32_bf16(a0, bf_, acck, 0, 0, 0);
            bf_ = *(const bf16x8*)&wa2t[dcol * 72 + 32 + qd * 8];
            acck = __builtin_amdgcn_mfma_f32_16x16x32_bf16(a1, bf_, acck, 0, 0, 0);

            _Float16 Ekf[4], ekf[4];
#pragma unroll
            for (int reg = 0; reg < 4; ++reg) {
                rho[reg] = __builtin_exp2f(accq[reg] * (-0.99f * LOG2E));
                float kp = acck[reg] * LOG2E;
                Ekf[reg] = (_Float16)__builtin_exp2f(kp);
                ekf[reg] = (_Float16)__builtin_exp2f(0.01f * kp);
            }
            if (i0 < NN) {   // rows >= 50 never read in phase 2 (p < 25)
                h2* kxP = (h2*)(kx + dcol * 116 + i0 * 2);   // 8B-aligned
                kxP[0] = (h2){Ekf[0], Ekf[1]};
                kxP[1] = (h2){ekf[0], ekf[1]};
                kxP[2] = (h2){Ekf[2], Ekf[3]};
                kxP[3] = (h2){ekf[2], ekf[3]};
            }
        }
        __syncthreads();

        // ---- phase 2: packed-f16 softmax-weighted sum, uniform 4 rows ----
        float att[4];
        {
            h2 rho2[4], num2[4], den2[4];
#pragma unroll
            for (int r = 0; r < 4; ++r) {
                _Float16 rv = (_Float16)rho[r];
                rho2[r] = (h2){rv, rv};
                num2[r] = (h2)0.f;
                den2[r] = (h2)0.f;
            }
            const h2* kxP = (const h2*)(kx + dcol * 116);
            const h2* xP  = (const h2*)(xt + dcol * 56);
            for (int p = 0; p < NN / 2; ++p) {
                h2 Ek2 = kxP[2 * p];        // adjacent 8B-aligned -> ds_read_b64
                h2 ek2 = kxP[2 * p + 1];
                h2 x2  = xP[p];
#pragma unroll
                for (int r = 0; r < 4; ++r) {
                    h2 wv = __builtin_elementwise_max(rho2[r] * ek2, Ek2);
                    den2[r] = den2[r] + wv;
                    num2[r] = wv * x2 + num2[r];        // v_pk_fma_f16
                }
            }
#pragma unroll
            for (int r = 0; r < 4; ++r) {
                float nu = (float)num2[r].x + (float)num2[r].y;
                float de = (float)den2[r].x + (float)den2[r].y;
                att[r] = nu / de;
            }
        }
        __syncthreads();                 // kx fully read -> safe to alias xb
#pragma unroll
        for (int reg = 0; reg < 4; ++reg)
            xb[(i0 + reg) * 72 + dcol] = (unsigned short)f2bfbits(att[reg]);
        __syncthreads();

        // ---- phase 3: y = att @ Wl + bl on MFMA ----
        // (xb pad rows hold garbage att: affects only discarded C-rows >= 50)
        {
            const bf16x8 c0 = *(const bf16x8*)&xb[(tm * 16 + ln) * 72 + qd * 8];
            const bf16x8 c1 = *(const bf16x8*)&xb[(tm * 16 + ln) * 72 + 32 + qd * 8];
            const float bov = (L ? b2 : b1)[dcol];
            f32x4 y = {bov, bov, bov, bov};

            bf16x8 bf_;
            bf_ = *(const bf16x8*)&wot[dcol * 72 + qd * 8];
            y = __builtin_amdgcn_mfma_f32_16x16x32_bf16(c0, bf_, y, 0, 0, 0);
            bf_ = *(const bf16x8*)&wot[dcol * 72 + 32 + qd * 8];
            y = __builtin_amdgcn_mfma_f32_16x16x32_bf16(c1, bf_, y, 0, 0, 0);

            if (L == 0) {
                // att1 -> xa (bf16 rows; pad-row garbage contained) + xt (guarded)
#pragma unroll
                for (int reg = 0; reg < 4; ++reg) {
                    const int i = i0 + reg;
                    xa[i * 72 + dcol] = (unsigned short)f2bfbits(y[reg]);
                    if (i < NN) xt[dcol * 56 + i] = (_Float16)y[reg];
                }
                __syncthreads();
            } else {
                // stage fp32 y over dead kx-tail/xt, then coalesced store
#pragma unroll
                for (int reg = 0; reg < 4; ++reg) {
                    const int i = i0 + reg;
                    if (i < NN) yF[i * 64 + dcol] = y[reg];
                }
                __syncthreads();
                for (int idx = tid; idx < NN * ND; idx += 1024) {
                    const int i  = idx >> 6;
                    const int dd = idx & 63;
                    float e0   = embB[dd];
                    float ie   = embB[ND + idx];
                    float att1 = bfu(xa[i * 72 + dd]);
                    float o    = fmaf(e0, ie, yF[idx] + att1);
                    o = fmaxf(o, 0.01f * o);
                    out[(size_t)b * (NN * ND) + idx] = o;
                }
            }
        }
    }
}

extern "C" void kernel_launch(void* const* d_in, const int* in_sizes, int n_in,
                              void* d_out, int out_size, void* d_ws, size_t ws_size,
                              hipStream_t stream) {
    const float* emb = (const float*)d_in[0];
    const float* wa1 = (const float*)d_in[1];
    const float* ba1 = (const float*)d_in[2];
    const float* wa2 = (const float*)d_in[3];
    const float* ba2 = (const float*)d_in[4];
    const float* w1  = (const float*)d_in[5];
    const float* b1  = (const float*)d_in[6];
    const float* w2  = (const float*)d_in[7];
    const float* b2  = (const float*)d_in[8];
    float* out = (float*)d_out;

    att2_kernel<<<NB, 1024, 0, stream>>>(emb, wa1, ba1, wa2, ba2, w1, b1, w2, b2, out);
}